// Round 1
// baseline (3263.815 us; speedup 1.0000x reference)
//
#include <hip/hip_runtime.h>
#include <math.h>

#define BB 8
#define CC 12
#define HH 384
#define WW 384
#define NPIX (HH*WW)
#define LAMF 0.05f
#define EPSF 1e-12f
#define NITER 10

typedef float2 c2;

__device__ __forceinline__ c2 mkc(float x, float y){ c2 r; r.x=x; r.y=y; return r; }
__device__ __forceinline__ c2 cadd(c2 a, c2 b){ return mkc(a.x+b.x, a.y+b.y); }
__device__ __forceinline__ c2 csub(c2 a, c2 b){ return mkc(a.x-b.x, a.y-b.y); }
__device__ __forceinline__ c2 cmul(c2 a, c2 b){ return mkc(a.x*b.x - a.y*b.y, a.x*b.y + a.y*b.x); }
// conj(a)*b
__device__ __forceinline__ c2 cmulcj(c2 a, c2 b){ return mkc(a.x*b.x + a.y*b.y, a.x*b.y - a.y*b.x); }
// s*a + b
__device__ __forceinline__ c2 cax(float s, c2 a, c2 b){ return mkc(fmaf(s,a.x,b.x), fmaf(s,a.y,b.y)); }
// a * (-i*d)
__device__ __forceinline__ c2 rot90(c2 a, float d){ return mkc(d*a.y, -d*a.x); }

template<int DIR> __device__ __forceinline__ void dft3(c2&a0,c2&a1,c2&a2){
  const float d=(float)DIR;
  c2 t=cadd(a1,a2), s=csub(a1,a2);
  c2 m=mkc(a0.x-0.5f*t.x, a0.y-0.5f*t.y);
  const float c=0.8660254037844386f*d;
  c2 w=mkc(c*s.y, -c*s.x);
  a0=cadd(a0,t); a1=cadd(m,w); a2=csub(m,w);
}
template<int DIR> __device__ __forceinline__ void dft6(c2 u[6]){
  c2 e0=u[0],e1=u[2],e2=u[4], o0=u[1],o1=u[3],o2=u[5];
  dft3<DIR>(e0,e1,e2); dft3<DIR>(o0,o1,o2);
  const float d=(float)DIR, q=0.8660254037844386f*d;
  c2 w1=mkc(0.5f,-q), w2=mkc(-0.5f,-q);
  c2 b1=cmul(w1,o1), b2=cmul(w2,o2);
  u[0]=cadd(e0,o0); u[3]=csub(e0,o0);
  u[1]=cadd(e1,b1); u[4]=csub(e1,b1);
  u[2]=cadd(e2,b2); u[5]=csub(e2,b2);
}
template<int DIR> __device__ __forceinline__ void dft8(c2 u[8]){
  const float d=(float)DIR;
  c2 t0=cadd(u[0],u[4]), t1=csub(u[0],u[4]);
  c2 t2=cadd(u[2],u[6]), t3=csub(u[2],u[6]);
  c2 E0=cadd(t0,t2), E2=csub(t0,t2);
  c2 r3=rot90(t3,d);
  c2 E1=cadd(t1,r3), E3=csub(t1,r3);
  c2 s0=cadd(u[1],u[5]), s1=csub(u[1],u[5]);
  c2 s2=cadd(u[3],u[7]), s3=csub(u[3],u[7]);
  c2 O0=cadd(s0,s2), O2v=csub(s0,s2);
  c2 r7=rot90(s3,d);
  c2 O1=cadd(s1,r7), O3=csub(s1,r7);
  const float rs=0.7071067811865476f;
  c2 w81=mkc(rs,-rs*d), w83=mkc(-rs,-rs*d);
  O1=cmul(w81,O1); O2v=rot90(O2v,d); O3=cmul(w83,O3);
  u[0]=cadd(E0,O0); u[4]=csub(E0,O0);
  u[1]=cadd(E1,O1); u[5]=csub(E1,O1);
  u[2]=cadd(E2,O2v); u[6]=csub(E2,O2v);
  u[3]=cadd(E3,O3); u[7]=csub(E3,O3);
}

__device__ __forceinline__ int pidx(int i){ return i + (i/48); }

__device__ __forceinline__ void make_tw(int t, c2 tw2[7], c2 tw3[7]){
  const float TP = 6.28318530717958647692f;
  int k2 = t % 6;
  #pragma unroll
  for (int j=1;j<8;j++){
    float s,c;
    sincosf(-TP*(float)(k2*j)*(1.0f/48.0f), &s, &c);
    tw2[j-1]=mkc(c,s);
    sincosf(-TP*(float)(t*j)*(1.0f/384.0f), &s, &c);
    tw3[j-1]=mkc(c,s);
  }
}

// Stockham FFT-384, radices 6,8,8. Input: u6[j] = x[t + 64j] (all 64 lanes).
// Output: o8[j] = X[t + 48j] for lanes t < 48.
// SA/SB are per-wave scratch (c2[392] each, padded addressing via pidx).
template<int DIR>
__device__ __forceinline__ void fft384(c2 u6[6], c2 o8[8], c2* SA, c2* SB,
                                       int t, const c2 tw2[7], const c2 tw3[7])
{
  dft6<DIR>(u6);
  #pragma unroll
  for (int j=0;j<6;j++) SA[pidx(6*t+j)] = u6[j];
  __syncthreads();
  if (t<48){
    c2 u[8];
    #pragma unroll
    for (int j=0;j<8;j++) u[j]=SA[pidx(t+48*j)];
    #pragma unroll
    for (int j=1;j<8;j++){
      c2 w=tw2[j-1]; if (DIR<0) w.y=-w.y;
      u[j]=cmul(u[j],w);
    }
    dft8<DIR>(u);
    int k=t%6; int base=(t-k)*8+k;
    #pragma unroll
    for (int j=0;j<8;j++) SB[pidx(base+6*j)]=u[j];
  }
  __syncthreads();
  if (t<48){
    c2 u[8];
    #pragma unroll
    for (int j=0;j<8;j++) u[j]=SB[pidx(t+48*j)];
    #pragma unroll
    for (int j=1;j<8;j++){
      c2 w=tw3[j-1]; if (DIR<0) w.y=-w.y;
      u[j]=cmul(u[j],w);
    }
    dft8<DIR>(u);
    #pragma unroll
    for (int j=0;j<8;j++) o8[j]=u[j];
  }
}

// K1: v = (MODE0: adj + lam*x | MODE1: r + beta*p_old, write p_new when c==0),
// cim = maps*v, row FFT along W, transposed write -> WK[b,c,w,h]
template<int MODE>
__global__ __launch_bounds__(256)
void k1_fwd(const c2* __restrict__ xin, const c2* __restrict__ adj,
            const c2* __restrict__ maps, c2* __restrict__ WK,
            const c2* __restrict__ rbuf, const c2* __restrict__ pin,
            c2* __restrict__ pout, const float* __restrict__ bNum,
            const float* __restrict__ bDen)
{
  __shared__ c2 tile[16][387];
  __shared__ c2 scratch[4][2][392];
  const int tid=threadIdx.x, t=tid&63, wv=tid>>6;
  const int NT=HH/16;
  int bid=blockIdx.x;
  int ht=bid%NT, c=(bid/NT)%CC, b=bid/(NT*CC);
  int h0=ht*16;
  c2 tw2[7], tw3[7]; make_tw(t,tw2,tw3);
  float beta=0.f;
  if (MODE==1) beta = bNum[b]/(bDen[b]+EPSF);
  c2* SA=scratch[wv][0];
  c2* SB=scratch[wv][1];
  const c2* mb = maps + (size_t)(b*CC+c)*NPIX;
  for (int i=0;i<4;i++){
    int rr=wv*4+i, h=h0+rr;
    size_t ro=((size_t)b*HH+h)*WW;
    const c2* mrow=mb+(size_t)h*WW;
    c2 u6[6];
    #pragma unroll
    for (int j=0;j<6;j++){
      int w=t+64*j;
      c2 v;
      if (MODE==0){
        v = cax(LAMF, xin[ro+w], adj[ro+w]);
      } else {
        v = cax(beta, pin[ro+w], rbuf[ro+w]);
        if (c==0) pout[ro+w]=v;
      }
      u6[j]=cmul(mrow[w], v);
    }
    c2 o8[8];
    fft384<1>(u6,o8,SA,SB,t,tw2,tw3);
    if (t<48){
      #pragma unroll
      for (int j=0;j<8;j++) tile[rr][t+48*j]=o8[j];
    }
  }
  __syncthreads();
  c2* wkc = WK + (size_t)(b*CC+c)*NPIX;
  int rl=tid&15, wg=tid>>4;
  for (int it=0;it<24;it++){
    int w=it*16+wg;
    wkc[(size_t)w*HH + h0 + rl] = tile[rl][w];
  }
}

// K2: per contiguous row (b,c,w): FFT along H, * maskT (incl 1/(H*W)), IFFT along H, in place
__global__ __launch_bounds__(256)
void k2_mid(c2* __restrict__ WK, const float* __restrict__ maskT)
{
  __shared__ c2 scratch[4][2][392];
  const int tid=threadIdx.x, t=tid&63, wv=tid>>6;
  const int NT=WW/16;
  int bid=blockIdx.x;
  int wt=bid%NT, c=(bid/NT)%CC, b=bid/(NT*CC);
  c2 tw2[7], tw3[7]; make_tw(t,tw2,tw3);
  c2* SA=scratch[wv][0]; c2* SB=scratch[wv][1];
  for (int i=0;i<4;i++){
    int w=wt*16+wv*4+i;
    c2* row = WK + ((size_t)(b*CC+c)*WW + w)*HH;
    const float* mrow = maskT + ((size_t)b*WW + w)*HH;
    c2 u6[6];
    #pragma unroll
    for (int j=0;j<6;j++) u6[j]=row[t+64*j];
    c2 o8[8];
    fft384<1>(u6,o8,SA,SB,t,tw2,tw3);
    __syncthreads();
    if (t<48){
      #pragma unroll
      for (int j=0;j<8;j++){
        float m=mrow[t+48*j];
        c2 v=o8[j];
        SB[t+48*j]=mkc(v.x*m, v.y*m);
      }
    }
    __syncthreads();
    #pragma unroll
    for (int j=0;j<6;j++) u6[j]=SB[t+64*j];
    __syncthreads();
    c2 o8b[8];
    fft384<-1>(u6,o8b,SA,SB,t,tw2,tw3);
    if (t<48){
      #pragma unroll
      for (int j=0;j<8;j++) row[t+48*j]=o8b[j];
    }
  }
}

// K3: gather transposed tiles, IFFT along W, conj(maps)*val summed over coils,
// + lam*v, write Ap (or r in INIT), accumulate per-batch dot via atomics.
template<int MODE>
__global__ __launch_bounds__(256)
void k3_inv(const c2* __restrict__ WK, const c2* __restrict__ maps,
            const c2* __restrict__ xin, const c2* __restrict__ adj,
            const c2* __restrict__ pin, c2* __restrict__ rbuf,
            c2* __restrict__ Apbuf, c2* __restrict__ xout,
            float* __restrict__ accslot)
{
  __shared__ c2 tile[8][387];
  __shared__ c2 scratch[4][2][392];
  const int tid=threadIdx.x, t=tid&63, wv=tid>>6;
  const int NT=HH/8;
  int bid=blockIdx.x;
  int ht=bid%NT, b=bid/NT;
  int h0=ht*8;
  c2 tw2[7],tw3[7]; make_tw(t,tw2,tw3);
  c2* SA=scratch[wv][0]; c2* SB=scratch[wv][1];
  c2 acc[2][8];
  #pragma unroll
  for(int a=0;a<2;a++){
    #pragma unroll
    for(int q=0;q<8;q++) acc[a][q]=mkc(0.f,0.f);
  }
  int jj=tid&7, wq=tid>>3;
  for (int c=0;c<CC;c++){
    const c2* wkc = WK + (size_t)(b*CC+c)*NPIX;
    __syncthreads();
    for (int it=0;it<12;it++){
      int w=it*32+wq;
      tile[jj][w]=wkc[(size_t)w*HH + h0 + jj];
    }
    __syncthreads();
    const c2* mb = maps + (size_t)(b*CC+c)*NPIX;
    #pragma unroll
    for (int rl=0;rl<2;rl++){
      int j=wv*2+rl, h=h0+j;
      c2 u6[6];
      #pragma unroll
      for (int q=0;q<6;q++) u6[q]=tile[j][t+64*q];
      c2 o8[8];
      fft384<-1>(u6,o8,SA,SB,t,tw2,tw3);
      if (t<48){
        const c2* mrow=mb+(size_t)h*WW;
        #pragma unroll
        for (int q=0;q<8;q++){
          acc[rl][q]=cadd(acc[rl][q], cmulcj(mrow[t+48*q], o8[q]));
        }
      }
    }
  }
  float partial=0.f;
  #pragma unroll
  for (int rl=0;rl<2;rl++){
    int h=h0+wv*2+rl;
    size_t ro=((size_t)b*HH+h)*WW;
    if (t<48){
      #pragma unroll
      for (int q=0;q<8;q++){
        int w=t+48*q;
        if (MODE==0){
          c2 rhs = cax(LAMF, xin[ro+w], adj[ro+w]);
          c2 Ap = cax(LAMF, rhs, acc[rl][q]);
          c2 rv = csub(rhs, Ap);
          rbuf[ro+w]=rv;
          xout[ro+w]=rhs;
          partial = fmaf(rv.x,rv.x,fmaf(rv.y,rv.y,partial));
        } else {
          c2 pv = pin[ro+w];
          c2 Ap = cax(LAMF, pv, acc[rl][q]);
          Apbuf[ro+w]=Ap;
          partial = fmaf(pv.x,Ap.x,fmaf(pv.y,Ap.y,partial));
        }
      }
    }
  }
  #pragma unroll
  for (int o=32;o>0;o>>=1) partial += __shfl_down(partial,o);
  if (t==0) atomicAdd(&accslot[b], partial);
}

// K4: alpha = rd_prev/(pAp+eps); x += alpha p; r -= alpha Ap; accumulate |r|^2
__global__ __launch_bounds__(256)
void k4_upd(c2* __restrict__ x, c2* __restrict__ rbuf,
            const c2* __restrict__ p, const c2* __restrict__ Ap,
            const float* __restrict__ rdPrev, const float* __restrict__ pApk,
            float* __restrict__ rdNew)
{
  const int PERB = NPIX/1024;
  int bid=blockIdx.x;
  int b=bid/PERB, blk=bid%PERB;
  float alpha = rdPrev[b]/(pApk[b]+EPSF);
  size_t base=(size_t)b*NPIX + (size_t)blk*1024 + threadIdx.x;
  float partial=0.f;
  #pragma unroll
  for (int i=0;i<4;i++){
    size_t idx=base + i*256;
    c2 pv=p[idx], apv=Ap[idx], xv=x[idx], rv=rbuf[idx];
    xv = cax(alpha, pv, xv);
    rv = cax(-alpha, apv, rv);
    x[idx]=xv; rbuf[idx]=rv;
    partial = fmaf(rv.x,rv.x,fmaf(rv.y,rv.y,partial));
  }
  #pragma unroll
  for (int o=32;o>0;o>>=1) partial += __shfl_down(partial,o);
  if ((threadIdx.x&63)==0) atomicAdd(&rdNew[b], partial);
}

__global__ void kzero(float* scal){ scal[threadIdx.x]=0.f; }

// maskT[b][w][h] = mask[b][h][w] * 1/(H*W)
__global__ __launch_bounds__(256)
void kmask(const float* __restrict__ mask, float* __restrict__ maskT)
{
  __shared__ float tile[32][33];
  int bid=blockIdx.x;
  int wt=bid%12, htl=(bid/12)%12, b=bid/144;
  int h0=htl*32, w0=wt*32;
  int tid=threadIdx.x;
  int wl=tid&31, hl=tid>>5;
  for (int it=0;it<4;it++){
    int h=h0+it*8+hl;
    tile[it*8+hl][wl]=mask[((size_t)b*HH+h)*WW + w0+wl];
  }
  __syncthreads();
  int hl2=tid&31, wl2=tid>>5;
  const float SC = 1.0f/((float)HH*(float)WW);
  for (int it=0;it<4;it++){
    int w=w0+it*8+wl2;
    maskT[((size_t)b*WW+w)*HH + h0+hl2] = SC*tile[hl2][it*8+wl2];
  }
}

extern "C" void kernel_launch(void* const* d_in, const int* in_sizes, int n_in,
                              void* d_out, int out_size, void* d_ws, size_t ws_size,
                              hipStream_t stream)
{
  const c2* xin=(const c2*)d_in[0];
  const c2* adj=(const c2*)d_in[1];
  const c2* maps=(const c2*)d_in[2];
  const float* mask=(const float*)d_in[3];
  c2* xout=(c2*)d_out;
  char* wsp=(char*)d_ws;
  size_t off=0;
  c2* WK=(c2*)(wsp+off);    off += (size_t)BB*CC*NPIX*sizeof(c2);   // 113.2 MB
  float* maskT=(float*)(wsp+off); off += (size_t)BB*NPIX*sizeof(float); // 4.7 MB
  c2* rbuf=(c2*)(wsp+off);  off += (size_t)BB*NPIX*sizeof(c2);
  c2* pA=(c2*)(wsp+off);    off += (size_t)BB*NPIX*sizeof(c2);
  c2* pB=(c2*)(wsp+off);    off += (size_t)BB*NPIX*sizeof(c2);
  c2* Apb=(c2*)(wsp+off);   off += (size_t)BB*NPIX*sizeof(c2);
  float* scal=(float*)(wsp+off);
  float* rd=scal;            // rd[k][b], k=0..10
  float* pAp=scal+11*BB;     // pAp[k][b], k=1..10
  float* zslot=scal+22*BB;   // zeros (beta=0 for iter 1)

  kzero<<<1,256,0,stream>>>(scal);
  kmask<<<BB*144,256,0,stream>>>(mask,maskT);

  // init: x0 = rhs = adj + lam*x ; r = rhs - Aop(rhs) ; rd0 = <r,r>
  k1_fwd<0><<<BB*CC*(HH/16),256,0,stream>>>(xin,adj,maps,WK,rbuf,pA,pB,zslot,zslot);
  k2_mid<<<BB*CC*(WW/16),256,0,stream>>>(WK,maskT);
  k3_inv<0><<<BB*(HH/8),256,0,stream>>>(WK,maps,xin,adj,pA,rbuf,Apb,xout,rd);

  for (int k=1;k<=NITER;k++){
    c2* pouT = (k&1)? pA: pB;
    c2* pinb = (k&1)? pB: pA;
    const float* bN = (k>=2)? rd+(size_t)(k-1)*BB : zslot;
    const float* bD = (k>=2)? rd+(size_t)(k-2)*BB : zslot;
    // p_k = r_{k-1} + beta*p_{k-1}; Aop(p_k) staged through WK
    k1_fwd<1><<<BB*CC*(HH/16),256,0,stream>>>(xin,adj,maps,WK,rbuf,pinb,pouT,bN,bD);
    k2_mid<<<BB*CC*(WW/16),256,0,stream>>>(WK,maskT);
    k3_inv<1><<<BB*(HH/8),256,0,stream>>>(WK,maps,xin,adj,pouT,rbuf,Apb,xout,pAp+(size_t)k*BB);
    k4_upd<<<BB*(NPIX/1024),256,0,stream>>>(xout,rbuf,pouT,Apb,rd+(size_t)(k-1)*BB,pAp+(size_t)k*BB,rd+(size_t)k*BB);
  }
}

// Round 3
// 2857.511 us; speedup vs baseline: 1.1422x; 1.1422x over previous
//
#include <hip/hip_runtime.h>
#include <math.h>

#define BB 8
#define CC 12
#define HH 384
#define WW 384
#define NPIX (HH*WW)
#define LAMF 0.05f
#define EPSF 1e-12f
#define NITER 10

typedef float2 c2;

__device__ __forceinline__ c2 mkc(float x, float y){ c2 r; r.x=x; r.y=y; return r; }
__device__ __forceinline__ c2 cadd(c2 a, c2 b){ return mkc(a.x+b.x, a.y+b.y); }
__device__ __forceinline__ c2 csub(c2 a, c2 b){ return mkc(a.x-b.x, a.y-b.y); }
__device__ __forceinline__ c2 cmul(c2 a, c2 b){ return mkc(a.x*b.x - a.y*b.y, a.x*b.y + a.y*b.x); }
// conj(a)*b
__device__ __forceinline__ c2 cmulcj(c2 a, c2 b){ return mkc(a.x*b.x + a.y*b.y, a.x*b.y - a.y*b.x); }
// s*a + b
__device__ __forceinline__ c2 cax(float s, c2 a, c2 b){ return mkc(fmaf(s,a.x,b.x), fmaf(s,a.y,b.y)); }
// a * (-i*d)
__device__ __forceinline__ c2 rot90(c2 a, float d){ return mkc(d*a.y, -d*a.x); }

// Wave-local LDS fence: drains this wave's DS queue and blocks compiler
// reordering of LDS ops across it. Replaces __syncthreads() for
// wave-private scratch (cross-lane data exchange within one wave64).
__device__ __forceinline__ void lds_fence(){
  asm volatile("s_waitcnt lgkmcnt(0)" ::: "memory");
}

template<int DIR> __device__ __forceinline__ void dft3(c2&a0,c2&a1,c2&a2){
  const float d=(float)DIR;
  c2 t=cadd(a1,a2), s=csub(a1,a2);
  c2 m=mkc(a0.x-0.5f*t.x, a0.y-0.5f*t.y);
  const float c=0.8660254037844386f*d;
  c2 w=mkc(c*s.y, -c*s.x);
  a0=cadd(a0,t); a1=cadd(m,w); a2=csub(m,w);
}
template<int DIR> __device__ __forceinline__ void dft6(c2 u[6]){
  c2 e0=u[0],e1=u[2],e2=u[4], o0=u[1],o1=u[3],o2=u[5];
  dft3<DIR>(e0,e1,e2); dft3<DIR>(o0,o1,o2);
  const float d=(float)DIR, q=0.8660254037844386f*d;
  c2 w1=mkc(0.5f,-q), w2=mkc(-0.5f,-q);
  c2 b1=cmul(w1,o1), b2=cmul(w2,o2);
  u[0]=cadd(e0,o0); u[3]=csub(e0,o0);
  u[1]=cadd(e1,b1); u[4]=csub(e1,b1);
  u[2]=cadd(e2,b2); u[5]=csub(e2,b2);
}
template<int DIR> __device__ __forceinline__ void dft8(c2 u[8]){
  const float d=(float)DIR;
  c2 t0=cadd(u[0],u[4]), t1=csub(u[0],u[4]);
  c2 t2=cadd(u[2],u[6]), t3=csub(u[2],u[6]);
  c2 E0=cadd(t0,t2), E2=csub(t0,t2);
  c2 r3=rot90(t3,d);
  c2 E1=cadd(t1,r3), E3=csub(t1,r3);
  c2 s0=cadd(u[1],u[5]), s1=csub(u[1],u[5]);
  c2 s2=cadd(u[3],u[7]), s3=csub(u[3],u[7]);
  c2 O0=cadd(s0,s2), O2v=csub(s0,s2);
  c2 r7=rot90(s3,d);
  c2 O1=cadd(s1,r7), O3=csub(s1,r7);
  const float rs=0.7071067811865476f;
  c2 w81=mkc(rs,-rs*d), w83=mkc(-rs,-rs*d);
  O1=cmul(w81,O1); O2v=rot90(O2v,d); O3=cmul(w83,O3);
  u[0]=cadd(E0,O0); u[4]=csub(E0,O0);
  u[1]=cadd(E1,O1); u[5]=csub(E1,O1);
  u[2]=cadd(E2,O2v); u[6]=csub(E2,O2v);
  u[3]=cadd(E3,O3); u[7]=csub(E3,O3);
}

__device__ __forceinline__ int pidx(int i){ return i + (i/48); }

// e^{-i*2*pi*rev} via hw transcendentals (v_sin/v_cos take revolutions)
__device__ __forceinline__ c2 twid(float rev){
  float r = rev - floorf(rev);
  return mkc(__builtin_amdgcn_cosf(r), -__builtin_amdgcn_sinf(r));
}

__device__ __forceinline__ void make_tw(int t, c2 tw2[7], c2 tw3[7]){
  int k2 = t % 6;
  #pragma unroll
  for (int j=1;j<8;j++){
    tw2[j-1] = twid((float)(k2*j) * (1.0f/48.0f));
    tw3[j-1] = twid((float)(t*j)  * (1.0f/384.0f));
  }
}

// Stockham FFT-384, radices 6,8,8. Wave-private scratch; lds_fence() at each
// phase boundary instead of block barriers (waves stay independent).
// Input: u6[j] = x[t + 64j] (all 64 lanes). Output: o8[j] = X[t + 48j], lanes t<48.
template<int DIR>
__device__ __forceinline__ void fft384(c2 u6[6], c2 o8[8], c2* SA, c2* SB,
                                       int t, const c2 tw2[7], const c2 tw3[7])
{
  dft6<DIR>(u6);
  #pragma unroll
  for (int j=0;j<6;j++) SA[pidx(6*t+j)] = u6[j];
  lds_fence();
  if (t<48){
    c2 u[8];
    #pragma unroll
    for (int j=0;j<8;j++) u[j]=SA[pidx(t+48*j)];
    #pragma unroll
    for (int j=1;j<8;j++){
      c2 w=tw2[j-1]; if (DIR<0) w.y=-w.y;
      u[j]=cmul(u[j],w);
    }
    dft8<DIR>(u);
    int k=t%6; int base=(t-k)*8+k;
    #pragma unroll
    for (int j=0;j<8;j++) SB[pidx(base+6*j)]=u[j];
    lds_fence();
    c2 v[8];
    #pragma unroll
    for (int j=0;j<8;j++) v[j]=SB[pidx(t+48*j)];
    #pragma unroll
    for (int j=1;j<8;j++){
      c2 w=tw3[j-1]; if (DIR<0) w.y=-w.y;
      v[j]=cmul(v[j],w);
    }
    dft8<DIR>(v);
    #pragma unroll
    for (int j=0;j<8;j++) o8[j]=v[j];
  }
}

// K1: v = (MODE0: adj + lam*x | MODE1: r + beta*p_old, write p_new when c==0),
// cim = maps*v, row FFT along W, transposed write -> WK[b,c,w,h]. 8 h-rows/block.
template<int MODE>
__global__ __launch_bounds__(256)
void k1_fwd(const c2* __restrict__ xin, const c2* __restrict__ adj,
            const c2* __restrict__ maps, c2* __restrict__ WK,
            const c2* __restrict__ rbuf, const c2* __restrict__ pin,
            c2* __restrict__ pout, const float* __restrict__ bNum,
            const float* __restrict__ bDen)
{
  __shared__ c2 tile[8][387];
  __shared__ c2 scratch[4][2][392];
  const int tid=threadIdx.x, t=tid&63, wv=tid>>6;
  const int NT=HH/8;
  int bid=blockIdx.x;
  int ht=bid%NT, c=(bid/NT)%CC, b=bid/(NT*CC);
  int h0=ht*8;
  c2 tw2[7], tw3[7]; make_tw(t,tw2,tw3);
  float beta=0.f;
  if (MODE==1) beta = bNum[b]/(bDen[b]+EPSF);
  c2* SA=scratch[wv][0];
  c2* SB=scratch[wv][1];
  const c2* mb = maps + (size_t)(b*CC+c)*NPIX;
  for (int i=0;i<2;i++){
    int rr=wv*2+i, h=h0+rr;
    size_t ro=((size_t)b*HH+h)*WW;
    const c2* mrow=mb+(size_t)h*WW;
    c2 u6[6];
    #pragma unroll
    for (int j=0;j<6;j++){
      int w=t+64*j;
      c2 v;
      if (MODE==0){
        v = cax(LAMF, xin[ro+w], adj[ro+w]);
      } else {
        v = cax(beta, pin[ro+w], rbuf[ro+w]);
        if (c==0) pout[ro+w]=v;
      }
      u6[j]=cmul(mrow[w], v);
    }
    c2 o8[8];
    fft384<1>(u6,o8,SA,SB,t,tw2,tw3);
    if (t<48){
      #pragma unroll
      for (int j=0;j<8;j++) tile[rr][t+48*j]=o8[j];
    }
  }
  __syncthreads();
  c2* wkc = WK + (size_t)(b*CC+c)*NPIX;
  int rl=tid&7, wg=tid>>3;
  for (int it=0;it<12;it++){
    int w=it*32+wg;
    wkc[(size_t)w*HH + h0 + rl] = tile[rl][w];
  }
}

// K2: per contiguous row (b,c,w): FFT along H, * maskT (incl 1/(H*W)), IFFT along H,
// in place. Fully wave-independent (no block barriers at all).
__global__ __launch_bounds__(256)
void k2_mid(c2* __restrict__ WK, const float* __restrict__ maskT)
{
  __shared__ c2 scratch[4][2][392];
  const int tid=threadIdx.x, t=tid&63, wv=tid>>6;
  const int NT=WW/16;
  int bid=blockIdx.x;
  int wt=bid%NT, c=(bid/NT)%CC, b=bid/(NT*CC);
  c2 tw2[7], tw3[7]; make_tw(t,tw2,tw3);
  c2* SA=scratch[wv][0]; c2* SB=scratch[wv][1];
  for (int i=0;i<4;i++){
    int w=wt*16+wv*4+i;
    c2* row = WK + ((size_t)(b*CC+c)*WW + w)*HH;
    const float* mrow = maskT + ((size_t)b*WW + w)*HH;
    c2 u6[6];
    #pragma unroll
    for (int j=0;j<6;j++) u6[j]=row[t+64*j];
    c2 o8[8];
    fft384<1>(u6,o8,SA,SB,t,tw2,tw3);
    if (t<48){
      #pragma unroll
      for (int j=0;j<8;j++){
        float m=mrow[t+48*j];
        c2 v=o8[j];
        SB[t+48*j]=mkc(v.x*m, v.y*m);
      }
    }
    lds_fence();
    #pragma unroll
    for (int j=0;j<6;j++) u6[j]=SB[t+64*j];
    c2 o8b[8];
    fft384<-1>(u6,o8b,SA,SB,t,tw2,tw3);
    if (t<48){
      #pragma unroll
      for (int j=0;j<8;j++) row[t+48*j]=o8b[j];
    }
  }
}

// K3: gather transposed tiles, IFFT along W, conj(maps)*val summed over coils,
// + lam*v, write Ap (or r in INIT), accumulate per-batch dot via atomics.
template<int MODE>
__global__ __launch_bounds__(256)
void k3_inv(const c2* __restrict__ WK, const c2* __restrict__ maps,
            const c2* __restrict__ xin, const c2* __restrict__ adj,
            const c2* __restrict__ pin, c2* __restrict__ rbuf,
            c2* __restrict__ Apbuf, c2* __restrict__ xout,
            float* __restrict__ accslot)
{
  __shared__ c2 tile[8][387];
  __shared__ c2 scratch[4][2][392];
  const int tid=threadIdx.x, t=tid&63, wv=tid>>6;
  const int NT=HH/8;
  int bid=blockIdx.x;
  int ht=bid%NT, b=bid/NT;
  int h0=ht*8;
  c2 tw2[7],tw3[7]; make_tw(t,tw2,tw3);
  c2* SA=scratch[wv][0]; c2* SB=scratch[wv][1];
  c2 acc[2][8];
  #pragma unroll
  for(int a=0;a<2;a++){
    #pragma unroll
    for(int q=0;q<8;q++) acc[a][q]=mkc(0.f,0.f);
  }
  int jj=tid&7, wq=tid>>3;
  for (int c=0;c<CC;c++){
    const c2* wkc = WK + (size_t)(b*CC+c)*NPIX;
    __syncthreads();   // all waves done reading tile from previous coil
    for (int it=0;it<12;it++){
      int w=it*32+wq;
      tile[jj][w]=wkc[(size_t)w*HH + h0 + jj];
    }
    __syncthreads();   // tile fully gathered
    const c2* mb = maps + (size_t)(b*CC+c)*NPIX;
    #pragma unroll
    for (int rl=0;rl<2;rl++){
      int j=wv*2+rl, h=h0+j;
      c2 u6[6];
      #pragma unroll
      for (int q=0;q<6;q++) u6[q]=tile[j][t+64*q];
      c2 o8[8];
      fft384<-1>(u6,o8,SA,SB,t,tw2,tw3);
      if (t<48){
        const c2* mrow=mb+(size_t)h*WW;
        #pragma unroll
        for (int q=0;q<8;q++){
          acc[rl][q]=cadd(acc[rl][q], cmulcj(mrow[t+48*q], o8[q]));
        }
      }
    }
  }
  float partial=0.f;
  #pragma unroll
  for (int rl=0;rl<2;rl++){
    int h=h0+wv*2+rl;
    size_t ro=((size_t)b*HH+h)*WW;
    if (t<48){
      #pragma unroll
      for (int q=0;q<8;q++){
        int w=t+48*q;
        if (MODE==0){
          c2 rhs = cax(LAMF, xin[ro+w], adj[ro+w]);
          c2 Ap = cax(LAMF, rhs, acc[rl][q]);
          c2 rv = csub(rhs, Ap);
          rbuf[ro+w]=rv;
          xout[ro+w]=rhs;
          partial = fmaf(rv.x,rv.x,fmaf(rv.y,rv.y,partial));
        } else {
          c2 pv = pin[ro+w];
          c2 Ap = cax(LAMF, pv, acc[rl][q]);
          Apbuf[ro+w]=Ap;
          partial = fmaf(pv.x,Ap.x,fmaf(pv.y,Ap.y,partial));
        }
      }
    }
  }
  #pragma unroll
  for (int o=32;o>0;o>>=1) partial += __shfl_down(partial,o);
  if (t==0) atomicAdd(&accslot[b], partial);
}

// K4: alpha = rd_prev/(pAp+eps); x += alpha p; r -= alpha Ap; accumulate |r|^2
__global__ __launch_bounds__(256)
void k4_upd(c2* __restrict__ x, c2* __restrict__ rbuf,
            const c2* __restrict__ p, const c2* __restrict__ Ap,
            const float* __restrict__ rdPrev, const float* __restrict__ pApk,
            float* __restrict__ rdNew)
{
  const int PERB = NPIX/1024;
  int bid=blockIdx.x;
  int b=bid/PERB, blk=bid%PERB;
  float alpha = rdPrev[b]/(pApk[b]+EPSF);
  size_t base=(size_t)b*NPIX + (size_t)blk*1024 + threadIdx.x;
  float partial=0.f;
  #pragma unroll
  for (int i=0;i<4;i++){
    size_t idx=base + i*256;
    c2 pv=p[idx], apv=Ap[idx], xv=x[idx], rv=rbuf[idx];
    xv = cax(alpha, pv, xv);
    rv = cax(-alpha, apv, rv);
    x[idx]=xv; rbuf[idx]=rv;
    partial = fmaf(rv.x,rv.x,fmaf(rv.y,rv.y,partial));
  }
  #pragma unroll
  for (int o=32;o>0;o>>=1) partial += __shfl_down(partial,o);
  if ((threadIdx.x&63)==0) atomicAdd(&rdNew[b], partial);
}

__global__ void kzero(float* scal){ scal[threadIdx.x]=0.f; }

// maskT[b][w][h] = mask[b][h][w] * 1/(H*W)
__global__ __launch_bounds__(256)
void kmask(const float* __restrict__ mask, float* __restrict__ maskT)
{
  __shared__ float tile[32][33];
  int bid=blockIdx.x;
  int wt=bid%12, htl=(bid/12)%12, b=bid/144;
  int h0=htl*32, w0=wt*32;
  int tid=threadIdx.x;
  int wl=tid&31, hl=tid>>5;
  for (int it=0;it<4;it++){
    int h=h0+it*8+hl;
    tile[it*8+hl][wl]=mask[((size_t)b*HH+h)*WW + w0+wl];
  }
  __syncthreads();
  int hl2=tid&31, wl2=tid>>5;
  const float SC = 1.0f/((float)HH*(float)WW);
  for (int it=0;it<4;it++){
    int w=w0+it*8+wl2;
    maskT[((size_t)b*WW+w)*HH + h0+hl2] = SC*tile[hl2][it*8+wl2];
  }
}

extern "C" void kernel_launch(void* const* d_in, const int* in_sizes, int n_in,
                              void* d_out, int out_size, void* d_ws, size_t ws_size,
                              hipStream_t stream)
{
  const c2* xin=(const c2*)d_in[0];
  const c2* adj=(const c2*)d_in[1];
  const c2* maps=(const c2*)d_in[2];
  const float* mask=(const float*)d_in[3];
  c2* xout=(c2*)d_out;
  char* wsp=(char*)d_ws;
  size_t off=0;
  c2* WK=(c2*)(wsp+off);    off += (size_t)BB*CC*NPIX*sizeof(c2);   // 113.2 MB
  float* maskT=(float*)(wsp+off); off += (size_t)BB*NPIX*sizeof(float); // 4.7 MB
  c2* rbuf=(c2*)(wsp+off);  off += (size_t)BB*NPIX*sizeof(c2);
  c2* pA=(c2*)(wsp+off);    off += (size_t)BB*NPIX*sizeof(c2);
  c2* pB=(c2*)(wsp+off);    off += (size_t)BB*NPIX*sizeof(c2);
  c2* Apb=(c2*)(wsp+off);   off += (size_t)BB*NPIX*sizeof(c2);
  float* scal=(float*)(wsp+off);
  float* rd=scal;            // rd[k][b], k=0..10
  float* pAp=scal+11*BB;     // pAp[k][b], k=1..10
  float* zslot=scal+22*BB;   // zeros (beta=0 for iter 1)

  kzero<<<1,256,0,stream>>>(scal);
  kmask<<<BB*144,256,0,stream>>>(mask,maskT);

  // init: x0 = rhs = adj + lam*x ; r = rhs - Aop(rhs) ; rd0 = <r,r>
  k1_fwd<0><<<BB*CC*(HH/8),256,0,stream>>>(xin,adj,maps,WK,rbuf,pA,pB,zslot,zslot);
  k2_mid<<<BB*CC*(WW/16),256,0,stream>>>(WK,maskT);
  k3_inv<0><<<BB*(HH/8),256,0,stream>>>(WK,maps,xin,adj,pA,rbuf,Apb,xout,rd);

  for (int k=1;k<=NITER;k++){
    c2* pouT = (k&1)? pA: pB;
    c2* pinb = (k&1)? pB: pA;
    const float* bN = (k>=2)? rd+(size_t)(k-1)*BB : zslot;
    const float* bD = (k>=2)? rd+(size_t)(k-2)*BB : zslot;
    // p_k = r_{k-1} + beta*p_{k-1}; Aop(p_k) staged through WK
    k1_fwd<1><<<BB*CC*(HH/8),256,0,stream>>>(xin,adj,maps,WK,rbuf,pinb,pouT,bN,bD);
    k2_mid<<<BB*CC*(WW/16),256,0,stream>>>(WK,maskT);
    k3_inv<1><<<BB*(HH/8),256,0,stream>>>(WK,maps,xin,adj,pouT,rbuf,Apb,xout,pAp+(size_t)k*BB);
    k4_upd<<<BB*(NPIX/1024),256,0,stream>>>(xout,rbuf,pouT,Apb,rd+(size_t)(k-1)*BB,pAp+(size_t)k*BB,rd+(size_t)k*BB);
  }
}